// Round 2
// baseline (147.994 us; speedup 1.0000x reference)
//
#include <hip/hip_runtime.h>

typedef __bf16 bf16x8 __attribute__((ext_vector_type(8)));
typedef float f32x4 __attribute__((ext_vector_type(4)));

#define CC 256
#define HH 48
#define WW 64
#define HW (HH * WW)
#define NB 8
#define GW 21

// ---------------------------------------------------------------------------
// Prepass: [B,C,H,W] fp32 -> [B,H*W,C] bf16 (RNE). in1 scaled by 2^-8 (exact)
// to fold /sumelems. Phase 1: coalesced scalar loads -> LDS [c][s] stride 33
// (conflict-free). Phase 2: lane c-index spans 64 -> 2-way (free) LDS reads,
// ushort stores coalesce to 128B/instr.
// ---------------------------------------------------------------------------
__global__ __launch_bounds__(256) void prep_kernel(const float* __restrict__ in1,
                                                   const float* __restrict__ in2,
                                                   unsigned short* __restrict__ o1,
                                                   unsigned short* __restrict__ o2)
{
    __shared__ float lds[CC * 33];
    int blk = blockIdx.x;
    int sel  = (blk >= 768);
    int blk2 = sel ? blk - 768 : blk;
    int b  = blk2 & 7;
    int st = blk2 >> 3;              // 0..95 spatial tile
    int s0 = st * 32;
    const float* src = sel ? in2 : in1;
    unsigned short* dst = sel ? o2 : o1;
    float scale = sel ? 1.0f : (1.0f / 256.0f);

    int t = threadIdx.x;
    int sidx = t & 31;
    int cbase = t >> 5;              // 0..7
    const float* sb = src + (size_t)b * CC * HW + s0;
    #pragma unroll
    for (int p = 0; p < 32; ++p) {
        int c = cbase + p * 8;
        lds[c * 33 + sidx] = sb[(size_t)c * HW + sidx] * scale;
    }
    __syncthreads();

    int c0  = t & 63;                // lane c spans 64 -> 2-way LDS reads (free)
    int sb2 = t >> 6;                // 0..3
    unsigned short* db = dst + ((size_t)b * HW + s0) * CC;
    #pragma unroll
    for (int p = 0; p < 8; ++p) {
        int s = sb2 + p * 4;         // 0..31
        #pragma unroll
        for (int ci = 0; ci < 4; ++ci) {
            int c = c0 + 64 * ci;
            unsigned u = __builtin_bit_cast(unsigned, lds[c * 33 + s]);
            u += 0x7fffu + ((u >> 16) & 1u);
            db[(size_t)s * CC + c] = (unsigned short)(u >> 16);
        }
    }
}

// ---------------------------------------------------------------------------
// Main: block = (b, ysrc), ysrc in [-20, 68). Valid ysrc: the full in2 row
// (64x256 bf16) is loaded ONCE into registers (Bf[4][8], 128 VGPR/lane).
// Each wave then loops over its j's (j = w + 4t), streaming A rows straight
// from global (L2-resident; b == blk&7 pins batch to one XCD) with a
// double-buffered k-loop. NO __syncthreads anywhere; epilogue uses a
// wave-private LDS transpose buffer. OOB ysrc blocks zero-fill.
// Grid: 8 * 88 = 704 blocks, 256 threads.
// ---------------------------------------------------------------------------
__global__ __launch_bounds__(256, 2) void corr_kernel(const unsigned short* __restrict__ in1T,
                                                      const unsigned short* __restrict__ in2T,
                                                      float* __restrict__ out)
{
    __shared__ float dbuf[4 * 2304];               // 4 wave-private D^T buffers
    int blk  = blockIdx.x;
    int b    = blk & 7;                            // batch == XCD affinity
    int ysrc = (blk >> 3) - 20;                    // in2 source row
    int tid  = threadIdx.x;

    if (ysrc < 0 || ysrc >= HH) {
        // zero-fill: output rows whose in2 source row is out of bounds
        for (int j = 0; j < GW; ++j) {
            int yo = ysrc - 2 * (j - 10);
            if (yo < 0 || yo >= HH) continue;
            float* ob = out + (((size_t)b * 441 + (size_t)j * GW) * HH + yo) * WW;
            for (int idx = tid; idx < GW * WW; idx += 256) {
                int jx = idx >> 6;
                int x  = idx & 63;
                __builtin_nontemporal_store(0.0f, ob + (size_t)jx * HW + x);
            }
        }
        return;
    }

    int w    = tid >> 6;
    int lane = tid & 63;
    int l15  = lane & 15;
    int q    = lane >> 4;

    // ---- B row resident in registers: Bf[nt][ks], lane holds B[n=l15+16nt][k=q*8+j]
    bf16x8 Bf[4][8];
    {
        const unsigned short* bl = in2T + ((size_t)(b * HH + ysrc) * WW + l15) * CC + q * 8;
        #pragma unroll
        for (int nt = 0; nt < 4; ++nt)
            #pragma unroll
            for (int ks = 0; ks < 8; ++ks)
                Bf[nt][ks] = *(const bf16x8*)(bl + (size_t)nt * 16 * CC + ks * 32);
    }

    float* dtw = dbuf + w * 2304;                  // wave-private [64 col][36]
    int xl  = lane & 31;
    int jxp = lane >> 5;

    for (int t = 0; t < 6; ++t) {
        int j = w + 4 * t;
        if (j > 20) continue;
        int yo = ysrc - 2 * (j - 10);
        if (yo < 0 || yo >= HH) continue;

        const unsigned short* al = in1T + ((size_t)((b * HH + yo) * WW) + l15) * CC + q * 8;

        f32x4 acc[4][4];
        #pragma unroll
        for (int mt = 0; mt < 4; ++mt)
            #pragma unroll
            for (int nt = 0; nt < 4; ++nt)
                acc[mt][nt] = (f32x4){0.f, 0.f, 0.f, 0.f};

        // double-buffered A-fragment k-loop (A streamed from global/L2)
        bf16x8 af[2][4];
        #pragma unroll
        for (int mt = 0; mt < 4; ++mt)
            af[0][mt] = *(const bf16x8*)(al + (size_t)mt * 16 * CC);
        #pragma unroll
        for (int ks = 0; ks < 8; ++ks) {
            if (ks < 7) {
                #pragma unroll
                for (int mt = 0; mt < 4; ++mt)
                    af[(ks + 1) & 1][mt] =
                        *(const bf16x8*)(al + (size_t)mt * 16 * CC + (ks + 1) * 32);
            }
            #pragma unroll
            for (int mt = 0; mt < 4; ++mt)
                #pragma unroll
                for (int nt = 0; nt < 4; ++nt)
                    acc[mt][nt] = __builtin_amdgcn_mfma_f32_16x16x32_bf16(
                        af[ks & 1][mt], Bf[nt][ks], acc[mt][nt], 0, 0, 0);
        }

        // epilogue: wave-private transpose + band extraction (no block sync)
        float* orow = out + (((size_t)b * 441 + (size_t)j * GW) * HH + yo) * WW;
        #pragma unroll
        for (int h = 0; h < 2; ++h) {
            #pragma unroll
            for (int mt2 = 0; mt2 < 2; ++mt2) {
                int mt = 2 * h + mt2;
                #pragma unroll
                for (int nt = 0; nt < 4; ++nt)
                    *(f32x4*)(dtw + (nt * 16 + l15) * 36 + mt2 * 16 + q * 4) = acc[mt][nt];
            }
            int x = h * 32 + xl;
            #pragma unroll
            for (int jj = 0; jj < 11; ++jj) {
                int jx = 2 * jj + jxp;
                if (jx >= GW) continue;
                int colx = x + 2 * (jx - 10);
                float v = (colx >= 0 && colx < WW) ? dtw[colx * 36 + xl] : 0.0f;
                __builtin_nontemporal_store(v, orow + (size_t)jx * HW + x);
            }
        }
    }
}

extern "C" void kernel_launch(void* const* d_in, const int* in_sizes, int n_in,
                              void* d_out, int out_size, void* d_ws, size_t ws_size,
                              hipStream_t stream)
{
    (void)in_sizes; (void)n_in; (void)out_size; (void)ws_size;
    const float* in1 = (const float*)d_in[0];
    const float* in2 = (const float*)d_in[1];
    float* out = (float*)d_out;

    unsigned short* in1T = (unsigned short*)d_ws;
    unsigned short* in2T = in1T + (size_t)NB * HW * CC;

    prep_kernel<<<dim3(1536), dim3(256), 0, stream>>>(in1, in2, in1T, in2T);
    corr_kernel<<<dim3(NB * 88), dim3(256), 0, stream>>>(in1T, in2T, out);
}

// Round 3
// 134.466 us; speedup vs baseline: 1.1006x; 1.1006x over previous
//
#include <hip/hip_runtime.h>

typedef __bf16 bf16x8 __attribute__((ext_vector_type(8)));
typedef float f32x4 __attribute__((ext_vector_type(4)));
typedef float f32x16 __attribute__((ext_vector_type(16)));

#define CC 256
#define HH 48
#define WW 64
#define HW (HH * WW)
#define NB 8
#define GW 21

// ---------------------------------------------------------------------------
// Prepass: in1 -> in1T row-major [b][s=y*64+x][c] bf16, scaled 2^-8 (exact).
//          in2 -> in2F MFMA-fragment order [b][y][cblk=c>>3][x][8c] bf16, so
//          corr's B loads are lane-linear 16B (perfectly coalesced).
// ---------------------------------------------------------------------------
__global__ __launch_bounds__(256) void prep_kernel(const float* __restrict__ in1,
                                                   const float* __restrict__ in2,
                                                   unsigned short* __restrict__ o1,
                                                   unsigned short* __restrict__ o2)
{
    __shared__ float lds[CC * 33];     // [c][s] stride 33: conflict-free
    int blk  = blockIdx.x;
    int sel  = (blk >= 768);
    int blk2 = sel ? blk - 768 : blk;
    int b  = blk2 & 7;
    int st = blk2 >> 3;                // 0..95 spatial tile (32 pixels)
    int s0 = st * 32;
    const float* src = sel ? in2 : in1;
    float scale = sel ? 1.0f : (1.0f / 256.0f);

    int t = threadIdx.x;
    int sidx  = t & 31;
    int cbase = t >> 5;
    const float* sb = src + (size_t)b * CC * HW + s0;
    #pragma unroll
    for (int p = 0; p < 32; ++p) {
        int c = cbase + p * 8;
        lds[c * 33 + sidx] = sb[(size_t)c * HW + sidx] * scale;
    }
    __syncthreads();

    if (!sel) {
        // in1T row-major: db[s*256 + c], coalesced 2B stores (c fast per lane)
        unsigned short* db = o1 + ((size_t)b * HW + s0) * CC;
        int c0  = t & 63;
        int sb2 = t >> 6;
        #pragma unroll
        for (int p = 0; p < 8; ++p) {
            int s = sb2 + p * 4;
            #pragma unroll
            for (int ci = 0; ci < 4; ++ci) {
                int c = c0 + 64 * ci;
                unsigned u = __builtin_bit_cast(unsigned, lds[c * 33 + s]);
                u += 0x7fffu + ((u >> 16) & 1u);
                db[(size_t)s * CC + c] = (unsigned short)(u >> 16);
            }
        }
    } else {
        // in2F fragment order: [(b*48+y)*32 + cblk][x][8]; 16B stores coalesced
        int y  = s0 >> 6;
        int xb = s0 & 63;              // 0 or 32
        int s  = t & 31;
        int c8 = t >> 5;               // 0..7
        unsigned short* db = o2 + (size_t)(b * HH + y) * 32 * 64 * 8;
        #pragma unroll
        for (int it = 0; it < 4; ++it) {
            int cblk = it * 8 + c8;
            unsigned dw[4];
            #pragma unroll
            for (int d = 0; d < 4; ++d) {
                unsigned u0 = __builtin_bit_cast(unsigned, lds[(cblk * 8 + 2 * d) * 33 + s]);
                u0 += 0x7fffu + ((u0 >> 16) & 1u);
                unsigned u1 = __builtin_bit_cast(unsigned, lds[(cblk * 8 + 2 * d + 1) * 33 + s]);
                u1 += 0x7fffu + ((u1 >> 16) & 1u);
                dw[d] = (u0 >> 16) | (u1 & 0xffff0000u);
            }
            *(uint4*)(db + ((size_t)cblk * 64 + xb + s) * 8) =
                make_uint4(dw[0], dw[1], dw[2], dw[3]);
        }
    }
}

// ---------------------------------------------------------------------------
// Main: one wave = one (b, ysrc, j) 64x64x256 GEMM, fully independent
// (NO barriers). D[x][x'] = sum_c A[x][c]*B[x'][c], A = in1T row yo,
// B = in2F row ysrc; out[b, j*21+jx, yo, x] = D[x][x+2(jx-10)].
// 32x32x16 MFMA, 2x2 tiles (64 acc regs). A,B double-buffered from
// global/L2 (b = blk&7 pins batch to one XCD; in1T[b]+in2F[b] = 3MB < 4MB L2).
// Waves of a block share ysrc -> same B row -> L1 broadcast.
// OOB-ysrc waves zero-fill. Grid: 8*88*6 = 4224 blocks.
// ---------------------------------------------------------------------------
__global__ __launch_bounds__(256, 4) void corr_kernel(const unsigned short* __restrict__ in1T,
                                                      const unsigned short* __restrict__ in2F,
                                                      float* __restrict__ out)
{
    __shared__ float dbuf[4 * 2304];             // per-wave D^T buffer [64][36]
    int blk  = blockIdx.x;
    int b    = blk & 7;                          // batch == XCD affinity
    int t2   = blk >> 3;
    int ysrc = (t2 % 88) - 20;
    int jg   = t2 / 88;                          // 0..5
    int tid  = threadIdx.x;
    int w    = tid >> 6;
    int lane = tid & 63;

    int j = jg * 4 + w;
    if (j > 20) return;                          // jg=5 has only j=20
    int yo = ysrc - 2 * (j - 10);
    if (yo < 0 || yo >= HH) return;              // (j,yo) pair doesn't exist

    float* orow = out + (((size_t)(b * 441 + j * GW)) * HH + yo) * WW;

    if (ysrc < 0 || ysrc >= HH) {
        // in2 source row OOB -> these 21 output rows are zero
        #pragma unroll
        for (int jx = 0; jx < GW; ++jx)
            orow[(size_t)jx * HW + lane] = 0.0f;
        return;
    }

    int l31 = lane & 31;
    int q2  = lane >> 5;                         // k-half within fragment

    // A[m = mt*32+l31][k = kk*16 + q2*8 + i]
    const unsigned short* arow =
        in1T + ((size_t)((b * HH + yo) * WW) + l31) * CC + q2 * 8;
    // B fragment (cblk = kk*2+q2, n = nt*32+l31), lane-linear 16B
    const unsigned short* brow =
        in2F + (((size_t)(b * HH + ysrc) * 32 + q2) * 64 + l31) * 8;

    f32x16 acc[2][2];
    #pragma unroll
    for (int mt = 0; mt < 2; ++mt)
        #pragma unroll
        for (int nt = 0; nt < 2; ++nt)
            acc[mt][nt] = (f32x16)(0.0f);

    bf16x8 Af[2][2], Bf[2][2];
    #pragma unroll
    for (int mt = 0; mt < 2; ++mt)
        Af[0][mt] = *(const bf16x8*)(arow + (size_t)mt * 32 * CC);
    #pragma unroll
    for (int nt = 0; nt < 2; ++nt)
        Bf[0][nt] = *(const bf16x8*)(brow + nt * 32 * 8);

    #pragma unroll
    for (int kk = 0; kk < 16; ++kk) {
        int cur = kk & 1, nxt = cur ^ 1;
        if (kk < 15) {
            #pragma unroll
            for (int mt = 0; mt < 2; ++mt)
                Af[nxt][mt] = *(const bf16x8*)(arow + (size_t)mt * 32 * CC + (kk + 1) * 16);
            #pragma unroll
            for (int nt = 0; nt < 2; ++nt)
                Bf[nxt][nt] = *(const bf16x8*)(brow + (size_t)(kk + 1) * 2 * 64 * 8 + nt * 32 * 8);
        }
        #pragma unroll
        for (int mt = 0; mt < 2; ++mt)
            #pragma unroll
            for (int nt = 0; nt < 2; ++nt)
                acc[mt][nt] = __builtin_amdgcn_mfma_f32_32x32x16_bf16(
                    Af[cur][mt], Bf[cur][nt], acc[mt][nt], 0, 0, 0);
    }

    // Epilogue: per x-half h (= mt), dump D^T into wave-private LDS, then
    // band-extract with coalesced 128B half-wave stores.
    // 32x32 C layout: col = l31 (n), row = (r&3) + 8*(r>>2) + 4*q2 (m).
    float* dtw = dbuf + w * 2304;
    #pragma unroll
    for (int h = 0; h < 2; ++h) {
        #pragma unroll
        for (int nt = 0; nt < 2; ++nt) {
            #pragma unroll
            for (int rq = 0; rq < 4; ++rq) {
                f32x4 v = { acc[h][nt][4 * rq], acc[h][nt][4 * rq + 1],
                            acc[h][nt][4 * rq + 2], acc[h][nt][4 * rq + 3] };
                *(f32x4*)(dtw + (nt * 32 + l31) * 36 + rq * 8 + q2 * 4) = v;
            }
        }
        int x = h * 32 + l31;
        #pragma unroll
        for (int jj = 0; jj < 11; ++jj) {
            int jx = 2 * jj + q2;
            if (jx >= GW) continue;
            int colx = x + 2 * (jx - 10);
            float v = (colx >= 0 && colx < WW) ? dtw[colx * 36 + l31] : 0.0f;
            orow[(size_t)jx * HW + x] = v;
        }
    }
}

extern "C" void kernel_launch(void* const* d_in, const int* in_sizes, int n_in,
                              void* d_out, int out_size, void* d_ws, size_t ws_size,
                              hipStream_t stream)
{
    (void)in_sizes; (void)n_in; (void)out_size; (void)ws_size;
    const float* in1 = (const float*)d_in[0];
    const float* in2 = (const float*)d_in[1];
    float* out = (float*)d_out;

    unsigned short* in1T = (unsigned short*)d_ws;                 // 12.6 MB
    unsigned short* in2F = in1T + (size_t)NB * HW * CC;           // 12.6 MB

    prep_kernel<<<dim3(1536), dim3(256), 0, stream>>>(in1, in2, in1T, in2F);
    corr_kernel<<<dim3(NB * 88 * 6), dim3(256), 0, stream>>>(in1T, in2F, out);
}

// Round 4
// 118.397 us; speedup vs baseline: 1.2500x; 1.1357x over previous
//
#include <hip/hip_runtime.h>

typedef __bf16 bf16x8 __attribute__((ext_vector_type(8)));
typedef float f32x4 __attribute__((ext_vector_type(4)));
typedef float f32x16 __attribute__((ext_vector_type(16)));

#define CC 256
#define HH 48
#define WW 64
#define HW (HH * WW)
#define NB 8
#define GW 21

// ---------------------------------------------------------------------------
// Prepass: BOTH inputs -> MFMA-fragment order [b][y][cblk=c>>3][x][c&7] bf16,
// so every k-loop operand load in corr is lane-linear 16B (coalesced).
// in1 scaled by 2^-8 (exact in bf16) to fold the /sumelems.
// Phase 1: coalesced loads -> LDS [c][s] stride 33 (conflict-free).
// Phase 2: pack 8 c's into uint4, 16B stores, 2-way LDS reads (free).
// ---------------------------------------------------------------------------
__global__ __launch_bounds__(256) void prep_kernel(const float* __restrict__ in1,
                                                   const float* __restrict__ in2,
                                                   unsigned short* __restrict__ o1,
                                                   unsigned short* __restrict__ o2)
{
    __shared__ float lds[CC * 33];
    int blk  = blockIdx.x;
    int sel  = (blk >= 768);
    int blk2 = sel ? blk - 768 : blk;
    int b  = blk2 & 7;
    int st = blk2 >> 3;                // 0..95 spatial tile (32 pixels)
    int s0 = st * 32;
    const float* src = sel ? in2 : in1;
    unsigned short* dst = sel ? o2 : o1;
    float scale = sel ? 1.0f : (1.0f / 256.0f);

    int t = threadIdx.x;
    int sidx  = t & 31;
    int cbase = t >> 5;
    const float* sb = src + (size_t)b * CC * HW + s0;
    #pragma unroll
    for (int p = 0; p < 32; ++p) {
        int c = cbase + p * 8;
        lds[c * 33 + sidx] = sb[(size_t)c * HW + sidx] * scale;
    }
    __syncthreads();

    // fragment order: [(b*48+y)*32 + cblk][x 0..63][8c]
    int y  = s0 >> 6;
    int xb = s0 & 63;                  // 0 or 32
    int s  = t & 31;
    int c8 = t >> 5;                   // 0..7
    unsigned short* db = dst + (size_t)(b * HH + y) * 32 * 64 * 8;
    #pragma unroll
    for (int it = 0; it < 4; ++it) {
        int cblk = it * 8 + c8;
        unsigned dw[4];
        #pragma unroll
        for (int d = 0; d < 4; ++d) {
            unsigned u0 = __builtin_bit_cast(unsigned, lds[(cblk * 8 + 2 * d) * 33 + s]);
            u0 += 0x7fffu + ((u0 >> 16) & 1u);
            unsigned u1 = __builtin_bit_cast(unsigned, lds[(cblk * 8 + 2 * d + 1) * 33 + s]);
            u1 += 0x7fffu + ((u1 >> 16) & 1u);
            dw[d] = (u0 >> 16) | (u1 & 0xffff0000u);
        }
        *(uint4*)(db + ((size_t)cblk * 64 + xb + s) * 8) =
            make_uint4(dw[0], dw[1], dw[2], dw[3]);
    }
}

// ---------------------------------------------------------------------------
// Main: one wave = one (b, ysrc, j) 64x64x256 GEMM, fully independent
// (NO barriers). D[x][x'] = sum_c A[x][c]*B[x'][c]; A = in1F row yo,
// B = in2F row ysrc; out[b, j*21+jx, yo, x] = D[x][x+2(jx-10)].
// 32x32x16 MFMA, 2x2 tiles (64 acc regs). BOTH operands now loaded from
// fragment-order global layout: lane-linear 16B/lane -> coalesced (this is
// the R3->R4 fix; R1-R3 A-loads hit 64 distinct cache lines/instr and
// serialized the L1 pipe at ~27us/CU aggregate).
// b = blk&7 pins batch to one XCD (3MB < 4MB L2); waves of a block share
// ysrc -> same B row -> L1 hits. Grid: 8*88*6 = 4224 blocks.
// ---------------------------------------------------------------------------
__global__ __launch_bounds__(256, 4) void corr_kernel(const unsigned short* __restrict__ in1F,
                                                      const unsigned short* __restrict__ in2F,
                                                      float* __restrict__ out)
{
    __shared__ float dbuf[4 * 2304];             // per-wave D^T buffer [64][36]
    int blk  = blockIdx.x;
    int b    = blk & 7;                          // batch == XCD affinity
    int t2   = blk >> 3;
    int ysrc = (t2 % 88) - 20;
    int jg   = t2 / 88;                          // 0..5
    int tid  = threadIdx.x;
    int w    = tid >> 6;
    int lane = tid & 63;

    int j = jg * 4 + w;
    if (j > 20) return;                          // jg=5 has only j=20
    int yo = ysrc - 2 * (j - 10);
    if (yo < 0 || yo >= HH) return;              // (j,yo) pair doesn't exist

    float* orow = out + (((size_t)(b * 441 + j * GW)) * HH + yo) * WW;

    if (ysrc < 0 || ysrc >= HH) {
        // in2 source row OOB -> these 21 output rows are zero
        #pragma unroll
        for (int jx = 0; jx < GW; ++jx)
            orow[(size_t)jx * HW + lane] = 0.0f;
        return;
    }

    int l31 = lane & 31;
    int q2  = lane >> 5;                         // k-half within fragment

    // A fragment (cblk = kk*2+q2, m = mt*32+l31): lane-linear 16B
    const unsigned short* arow =
        in1F + (((size_t)(b * HH + yo) * 32 + q2) * 64 + l31) * 8;
    // B fragment (cblk = kk*2+q2, n = nt*32+l31): lane-linear 16B
    const unsigned short* brow =
        in2F + (((size_t)(b * HH + ysrc) * 32 + q2) * 64 + l31) * 8;

    f32x16 acc[2][2];
    #pragma unroll
    for (int mt = 0; mt < 2; ++mt)
        #pragma unroll
        for (int nt = 0; nt < 2; ++nt)
            acc[mt][nt] = (f32x16)(0.0f);

    bf16x8 Af[2][2], Bf[2][2];
    #pragma unroll
    for (int mt = 0; mt < 2; ++mt)
        Af[0][mt] = *(const bf16x8*)(arow + mt * 32 * 8);
    #pragma unroll
    for (int nt = 0; nt < 2; ++nt)
        Bf[0][nt] = *(const bf16x8*)(brow + nt * 32 * 8);

    #pragma unroll
    for (int kk = 0; kk < 16; ++kk) {
        int cur = kk & 1, nxt = cur ^ 1;
        if (kk < 15) {
            #pragma unroll
            for (int mt = 0; mt < 2; ++mt)
                Af[nxt][mt] = *(const bf16x8*)(arow + (size_t)(kk + 1) * 1024 + mt * 32 * 8);
            #pragma unroll
            for (int nt = 0; nt < 2; ++nt)
                Bf[nxt][nt] = *(const bf16x8*)(brow + (size_t)(kk + 1) * 1024 + nt * 32 * 8);
        }
        #pragma unroll
        for (int mt = 0; mt < 2; ++mt)
            #pragma unroll
            for (int nt = 0; nt < 2; ++nt)
                acc[mt][nt] = __builtin_amdgcn_mfma_f32_32x32x16_bf16(
                    Af[cur][mt], Bf[cur][nt], acc[mt][nt], 0, 0, 0);
    }

    // Epilogue: per x-half h (= mt), dump D^T into wave-private LDS, then
    // band-extract with coalesced 128B half-wave stores.
    // 32x32 C layout: col = l31 (n), row = (r&3) + 8*(r>>2) + 4*q2 (m).
    float* dtw = dbuf + w * 2304;
    #pragma unroll
    for (int h = 0; h < 2; ++h) {
        #pragma unroll
        for (int nt = 0; nt < 2; ++nt) {
            #pragma unroll
            for (int rq = 0; rq < 4; ++rq) {
                f32x4 v = { acc[h][nt][4 * rq], acc[h][nt][4 * rq + 1],
                            acc[h][nt][4 * rq + 2], acc[h][nt][4 * rq + 3] };
                *(f32x4*)(dtw + (nt * 32 + l31) * 36 + rq * 8 + q2 * 4) = v;
            }
        }
        int x = h * 32 + l31;
        #pragma unroll
        for (int jj = 0; jj < 11; ++jj) {
            int jx = 2 * jj + q2;
            if (jx >= GW) continue;
            int colx = x + 2 * (jx - 10);
            float v = (colx >= 0 && colx < WW) ? dtw[colx * 36 + l31] : 0.0f;
            orow[(size_t)jx * HW + x] = v;
        }
    }
}

extern "C" void kernel_launch(void* const* d_in, const int* in_sizes, int n_in,
                              void* d_out, int out_size, void* d_ws, size_t ws_size,
                              hipStream_t stream)
{
    (void)in_sizes; (void)n_in; (void)out_size; (void)ws_size;
    const float* in1 = (const float*)d_in[0];
    const float* in2 = (const float*)d_in[1];
    float* out = (float*)d_out;

    unsigned short* in1F = (unsigned short*)d_ws;                 // 12.6 MB
    unsigned short* in2F = in1F + (size_t)NB * HW * CC;           // 12.6 MB

    prep_kernel<<<dim3(1536), dim3(256), 0, stream>>>(in1, in2, in1F, in2F);
    corr_kernel<<<dim3(NB * 88 * 6), dim3(256), 0, stream>>>(in1F, in2F, out);
}

// Round 5
// 118.318 us; speedup vs baseline: 1.2508x; 1.0007x over previous
//
#include <hip/hip_runtime.h>

typedef __bf16 bf16x8 __attribute__((ext_vector_type(8)));
typedef float f32x4 __attribute__((ext_vector_type(4)));
typedef float f32x16 __attribute__((ext_vector_type(16)));

#define CC 256
#define HH 48
#define WW 64
#define HW (HH * WW)
#define NB 8
#define GW 21

// ---------------------------------------------------------------------------
// Prepass: BOTH inputs -> MFMA-fragment order [b][y][cblk=c>>3][x][c&7] bf16,
// so every k-loop operand load in corr is lane-linear 16B (coalesced).
// in1 scaled by 2^-8 (exact in bf16) to fold the /sumelems.
// ---------------------------------------------------------------------------
__global__ __launch_bounds__(256) void prep_kernel(const float* __restrict__ in1,
                                                   const float* __restrict__ in2,
                                                   unsigned short* __restrict__ o1,
                                                   unsigned short* __restrict__ o2)
{
    __shared__ float lds[CC * 33];
    int blk  = blockIdx.x;
    int sel  = (blk >= 768);
    int blk2 = sel ? blk - 768 : blk;
    int b  = blk2 & 7;
    int st = blk2 >> 3;                // 0..95 spatial tile (32 pixels)
    int s0 = st * 32;
    const float* src = sel ? in2 : in1;
    unsigned short* dst = sel ? o2 : o1;
    float scale = sel ? 1.0f : (1.0f / 256.0f);

    int t = threadIdx.x;
    int sidx  = t & 31;
    int cbase = t >> 5;
    const float* sb = src + (size_t)b * CC * HW + s0;
    #pragma unroll
    for (int p = 0; p < 32; ++p) {
        int c = cbase + p * 8;
        lds[c * 33 + sidx] = sb[(size_t)c * HW + sidx] * scale;
    }
    __syncthreads();

    // fragment order: [(b*48+y)*32 + cblk][x 0..63][8c]
    int y  = s0 >> 6;
    int xb = s0 & 63;                  // 0 or 32
    int s  = t & 31;
    int c8 = t >> 5;                   // 0..7
    unsigned short* db = dst + (size_t)(b * HH + y) * 32 * 64 * 8;
    #pragma unroll
    for (int it = 0; it < 4; ++it) {
        int cblk = it * 8 + c8;
        unsigned dw[4];
        #pragma unroll
        for (int d = 0; d < 4; ++d) {
            unsigned u0 = __builtin_bit_cast(unsigned, lds[(cblk * 8 + 2 * d) * 33 + s]);
            u0 += 0x7fffu + ((u0 >> 16) & 1u);
            unsigned u1 = __builtin_bit_cast(unsigned, lds[(cblk * 8 + 2 * d + 1) * 33 + s]);
            u1 += 0x7fffu + ((u1 >> 16) & 1u);
            dw[d] = (u0 >> 16) | (u1 & 0xffff0000u);
        }
        *(uint4*)(db + ((size_t)cblk * 64 + xb + s) * 8) =
            make_uint4(dw[0], dw[1], dw[2], dw[3]);
    }
}

// ---------------------------------------------------------------------------
// Main: block = (b, ysrc, jg); 4 waves = 4 consecutive j. B row (32KB,
// fragment order) staged ONCE per block in LDS and shared by the 4 waves
// (cuts B L1/L2 traffic 4x vs R4 and stops B thrashing the 32KB L1).
// A streamed from global (fragment order, lane-linear 16B) with prefetch
// distance 2. One wave = one 64x64x256 GEMM via 32x32x16 MFMA 2x2 tiles.
// Epilogue reuses the B LDS region (barrier in between) as per-wave D^T
// transpose buffers; output stores are nontemporal so the 43MB write
// stream doesn't evict the 3MB/XCD A/B working set from L2.
// b = blk&7 pins batch to one XCD. Grid: 8*88*6 = 4224 blocks.
// ---------------------------------------------------------------------------
__global__ __launch_bounds__(256, 4) void corr_kernel(const unsigned short* __restrict__ in1F,
                                                      const unsigned short* __restrict__ in2F,
                                                      float* __restrict__ out)
{
    __shared__ unsigned char smem[36864];        // B-stage 32KB, then 4x9216B D^T
    unsigned short* Bl = (unsigned short*)smem;

    int blk  = blockIdx.x;
    int b    = blk & 7;                          // batch == XCD affinity
    int t2   = blk >> 3;
    int ysrc = (t2 % 88) - 20;
    int jg   = t2 / 88;                          // 0..5
    int tid  = threadIdx.x;
    int w    = tid >> 6;
    int lane = tid & 63;

    int j  = jg * 4 + w;
    int yo = ysrc - 2 * (j - 10);
    bool jvalid = (j <= 20) && (yo >= 0) && (yo < HH);

    float* orow = jvalid
        ? out + (((size_t)(b * 441 + j * GW)) * HH + yo) * WW
        : out;

    if (ysrc < 0 || ysrc >= HH) {
        // in2 source row OOB -> these 21 output rows are zero
        if (jvalid) {
            #pragma unroll
            for (int jx = 0; jx < GW; ++jx)
                __builtin_nontemporal_store(0.0f, orow + (size_t)jx * HW + lane);
        }
        return;                                  // whole block exits before barriers
    }

    // ---- stage B row (fragment order, linear 32KB copy) ----
    {
        const unsigned short* bsrc = in2F + (size_t)(b * HH + ysrc) * (32 * 64 * 8);
        #pragma unroll
        for (int it = 0; it < 8; ++it) {
            size_t off = ((size_t)it * 256 + tid) * 8;   // ushorts; 16B/thread
            *(uint4*)(Bl + off) = *(const uint4*)(bsrc + off);
        }
    }
    __syncthreads();

    int l31 = lane & 31;
    int q2  = lane >> 5;

    f32x16 acc[2][2];
    if (jvalid) {
        // A fragment (cblk = kk*2+q2, m = mt*32+l31): lane-linear 16B
        const unsigned short* arow =
            in1F + (((size_t)(b * HH + yo) * 32 + q2) * 64 + l31) * 8;
        // B fragment from LDS, same indexing
        const unsigned short* brow = Bl + ((size_t)q2 * 64 + l31) * 8;

        #pragma unroll
        for (int mt = 0; mt < 2; ++mt)
            #pragma unroll
            for (int nt = 0; nt < 2; ++nt)
                acc[mt][nt] = (f32x16)(0.0f);

        bf16x8 Ab[3][2], Bb[2][2];
        #pragma unroll
        for (int mt = 0; mt < 2; ++mt) {
            Ab[0][mt] = *(const bf16x8*)(arow + mt * 256);
            Ab[1][mt] = *(const bf16x8*)(arow + 1024 + mt * 256);
        }
        #pragma unroll
        for (int nt = 0; nt < 2; ++nt)
            Bb[0][nt] = *(const bf16x8*)(brow + nt * 256);

        #pragma unroll
        for (int kk = 0; kk < 16; ++kk) {
            if (kk < 14) {
                #pragma unroll
                for (int mt = 0; mt < 2; ++mt)
                    Ab[(kk + 2) % 3][mt] =
                        *(const bf16x8*)(arow + (size_t)(kk + 2) * 1024 + mt * 256);
            }
            if (kk < 15) {
                #pragma unroll
                for (int nt = 0; nt < 2; ++nt)
                    Bb[(kk + 1) & 1][nt] =
                        *(const bf16x8*)(brow + (size_t)(kk + 1) * 1024 + nt * 256);
            }
            #pragma unroll
            for (int mt = 0; mt < 2; ++mt)
                #pragma unroll
                for (int nt = 0; nt < 2; ++nt)
                    acc[mt][nt] = __builtin_amdgcn_mfma_f32_32x32x16_bf16(
                        Ab[kk % 3][mt], Bb[kk & 1][nt], acc[mt][nt], 0, 0, 0);
        }
    }

    __syncthreads();                             // B region dead; reuse for D^T

    if (!jvalid) return;

    // Epilogue: per x-half h, dump D^T into wave-private LDS, band-extract.
    // 32x32 C layout: col = l31 (n), row = (r&3) + 8*(r>>2) + 4*q2 (m).
    float* dtw = (float*)smem + w * 2304;        // [64 col][36] per wave
    #pragma unroll
    for (int h = 0; h < 2; ++h) {
        #pragma unroll
        for (int nt = 0; nt < 2; ++nt) {
            #pragma unroll
            for (int rq = 0; rq < 4; ++rq) {
                f32x4 v = { acc[h][nt][4 * rq], acc[h][nt][4 * rq + 1],
                            acc[h][nt][4 * rq + 2], acc[h][nt][4 * rq + 3] };
                *(f32x4*)(dtw + (nt * 32 + l31) * 36 + rq * 8 + q2 * 4) = v;
            }
        }
        int x = h * 32 + l31;
        #pragma unroll
        for (int jj = 0; jj < 11; ++jj) {
            int jx = 2 * jj + q2;
            if (jx >= GW) continue;
            int colx = x + 2 * (jx - 10);
            float v = (colx >= 0 && colx < WW) ? dtw[colx * 36 + l31] : 0.0f;
            __builtin_nontemporal_store(v, orow + (size_t)jx * HW + x);
        }
    }
}

extern "C" void kernel_launch(void* const* d_in, const int* in_sizes, int n_in,
                              void* d_out, int out_size, void* d_ws, size_t ws_size,
                              hipStream_t stream)
{
    (void)in_sizes; (void)n_in; (void)out_size; (void)ws_size;
    const float* in1 = (const float*)d_in[0];
    const float* in2 = (const float*)d_in[1];
    float* out = (float*)d_out;

    unsigned short* in1F = (unsigned short*)d_ws;                 // 12.6 MB
    unsigned short* in2F = in1F + (size_t)NB * HW * CC;           // 12.6 MB

    prep_kernel<<<dim3(1536), dim3(256), 0, stream>>>(in1, in2, in1F, in2F);
    corr_kernel<<<dim3(NB * 88 * 6), dim3(256), 0, stream>>>(in1F, in2F, out);
}